// Round 1
// baseline (6862.373 us; speedup 1.0000x reference)
//
#include <hip/hip_runtime.h>
#include <math.h>

#define N_ROWS 4096
#define DIM    128
#define A_LAB  512
#define INV_TAU 14.285714285714286f
#define THR 0.3f

// ---------------- workspace layout (bytes) ----------------
// zall  f32 [8192*128]          @ 0          (4,194,304)
// bm    u64 [4096*8]            @ 4,194,304  (262,144)
// s     f32 [4096]              @ 4,456,448  (16,384)
// pm    u32 [4096*128]          @ 4,472,832  (2,097,152)
// part  f32 [3*8*4096]          @ 6,569,984  (393,216)   total ~6.64 MB

// ---------------- kernel 1: L2-normalize + bit-pack labels ----------------
__global__ __launch_bounds__(64) void k_norm_pack(
    const float* __restrict__ z1, const float* __restrict__ z2,
    const int* __restrict__ labels,
    float* __restrict__ zall, unsigned long long* __restrict__ bm,
    float* __restrict__ s)
{
  const int r = blockIdx.x;           // 0..8191
  const int t = threadIdx.x;          // 0..63 (one wave)
  const float* src = (r < N_ROWS) ? (z1 + (size_t)r * DIM)
                                  : (z2 + (size_t)(r - N_ROWS) * DIM);
  float2 x = *(const float2*)(src + 2 * t);
  float ss = x.x * x.x + x.y * x.y;
  #pragma unroll
  for (int off = 32; off > 0; off >>= 1) ss += __shfl_xor(ss, off);
  const float inv = 1.0f / fmaxf(sqrtf(ss), 1e-12f);
  float2 y; y.x = x.x * inv; y.y = x.y * inv;
  *(float2*)(zall + (size_t)r * DIM + 2 * t) = y;

  if (r < N_ROWS) {
    const int* lab = labels + (size_t)r * A_LAB;
    unsigned long long myword = 0ull;
    #pragma unroll
    for (int c = 0; c < 8; ++c) {
      unsigned long long mm = __ballot(lab[c * 64 + t] != 0);
      if (t == c) myword = mm;
    }
    int p = (t < 8) ? __popcll(myword) : 0;
    #pragma unroll
    for (int off = 32; off > 0; off >>= 1) p += __shfl_xor(p, off);
    if (t < 8) bm[(size_t)r * 8 + t] = myword;
    if (t == 0) s[r] = (float)p;
  }
}

// ---------------- kernel 2: Jaccard positive mask (bit per pair) ----------------
__global__ __launch_bounds__(256) void k_posmask(
    const unsigned int* __restrict__ bm, const float* __restrict__ s,
    unsigned int* __restrict__ pm)
{
  const int g = blockIdx.x * 256 + threadIdx.x;  // 0..524287 == i*128+w
  const int i = g >> 7;
  const int w = g & 127;
  const uint4* bi = (const uint4*)(bm + (size_t)i * 16);
  const uint4 a0 = bi[0], a1 = bi[1], a2 = bi[2], a3 = bi[3];
  const float si = s[i];
  unsigned int bits = 0u;
  int jc = w << 5;
  for (int jj = 0; jj < 32; ++jj, ++jc) {
    const uint4* bj = (const uint4*)(bm + (size_t)jc * 16);
    const uint4 b0 = bj[0], b1 = bj[1], b2 = bj[2], b3 = bj[3];
    int inter = __popc(a0.x & b0.x) + __popc(a0.y & b0.y)
              + __popc(a0.z & b0.z) + __popc(a0.w & b0.w)
              + __popc(a1.x & b1.x) + __popc(a1.y & b1.y)
              + __popc(a1.z & b1.z) + __popc(a1.w & b1.w)
              + __popc(a2.x & b2.x) + __popc(a2.y & b2.y)
              + __popc(a2.z & b2.z) + __popc(a2.w & b2.w)
              + __popc(a3.x & b3.x) + __popc(a3.y & b3.y)
              + __popc(a3.z & b3.z) + __popc(a3.w & b3.w);
    const float fin = (float)inter;
    const float un = si + s[jc] - fin;
    const float jac = fin / (un + 1e-8f);
    if (jac >= THR) bits |= (1u << jj);
  }
  pm[g] = bits;
}

// k-quad XOR swizzle: element (col, k) of a 64x128 tile lives at
// col*128 + 4*((k/4) ^ ((col/4)&7)) + (k%4). float4-granular in k.
__device__ __forceinline__ int swz(int col, int q) {
  return col * 128 + ((q ^ ((col >> 2) & 7)) << 2);
}

// ---------------- kernel 3: fused sim-GEMM + masked softmax partials ----------------
__global__ __launch_bounds__(256, 2) void k_main(
    const float* __restrict__ zall, const unsigned int* __restrict__ pm,
    float* __restrict__ part)
{
  __shared__ float lds_a[64 * 128];   // 32 KB anchors
  __shared__ float lds_b[64 * 128];   // 32 KB columns
  const int tid = threadIdx.x;
  const int abase = blockIdx.x * 64;  // 64 anchor tiles
  const int sl = blockIdx.y;          // 8 column slices of 1024 cols
  const int ti = tid >> 4, tj = tid & 15;

  // stage A tile (once per block)
  {
    const int rowb = tid >> 5, m = tid & 31;
    #pragma unroll
    for (int r8 = 0; r8 < 8; ++r8) {
      const int row = rowb + (r8 << 3);
      const float4 v = *(const float4*)(zall + (size_t)(abase + row) * 128 + (m << 2));
      *(float4*)(lds_a + swz(row, m)) = v;
    }
  }

  float lacc[4] = {0,0,0,0}, Sacc[4] = {0,0,0,0}, Pacc[4] = {0,0,0,0};

  for (int ct = 0; ct < 16; ++ct) {
    const int colbase = sl * 1024 + ct * 64;
    __syncthreads();  // previous-iter readers done before overwriting lds_b
    {
      const int rowb = tid >> 5, m = tid & 31;
      #pragma unroll
      for (int r8 = 0; r8 < 8; ++r8) {
        const int row = rowb + (r8 << 3);
        const float4 v = *(const float4*)(zall + (size_t)(colbase + row) * 128 + (m << 2));
        *(float4*)(lds_b + swz(row, m)) = v;
      }
    }
    __syncthreads();

    float acc[4][4];
    #pragma unroll
    for (int u = 0; u < 4; ++u)
      #pragma unroll
      for (int v = 0; v < 4; ++v) acc[u][v] = 0.0f;

    #pragma unroll
    for (int q = 0; q < 32; ++q) {   // k = 4*q .. 4*q+3
      float4 af[4], bf[4];
      #pragma unroll
      for (int u = 0; u < 4; ++u) af[u] = *(const float4*)(lds_a + swz(4 * ti + u, q));
      #pragma unroll
      for (int v = 0; v < 4; ++v) bf[v] = *(const float4*)(lds_b + swz(4 * tj + v, q));
      #pragma unroll
      for (int u = 0; u < 4; ++u)
        #pragma unroll
        for (int v = 0; v < 4; ++v)
          acc[u][v] += af[u].x * bf[v].x + af[u].y * bf[v].y
                     + af[u].z * bf[v].z + af[u].w * bf[v].w;
    }

    // epilogue: fixed shift m = 1/tau (loss is shift-invariant); skip self col
    #pragma unroll
    for (int v = 0; v < 4; ++v) {
      const int j = colbase + 4 * tj + v;       // 0..8191 over z_all
      const int jc = j & (N_ROWS - 1);
      const int wq = jc >> 5;
      const unsigned int bsel = 1u << (jc & 31);
      const bool left = (j < N_ROWS);
      #pragma unroll
      for (int u = 0; u < 4; ++u) {
        const int i = abase + 4 * ti + u;
        const float d = acc[u][v];              // dot in [-1,1]
        const unsigned int word = pm[(size_t)i * 128 + wq];
        const bool bit = (word & bsel) != 0u;
        // left half: jaccard positives minus diagonal; right half: plus forced aug col
        const bool pos = left ? (bit && (j != i)) : (bit || (jc == i));
        const float e = __expf((d - 1.0f) * INV_TAU);
        if (!(left && j == i)) lacc[u] += e;    // denominator excludes self col
        if (pos) { Sacc[u] += d; Pacc[u] += 1.0f; }
      }
    }
  }

  // reduce partials across the 16 tj threads sharing each anchor (reuse lds_a)
  float* red = lds_a;
  float* pl = part;
  float* pS = part + 8 * 4096;
  float* pP = part + 16 * 4096;
  __syncthreads();
  #pragma unroll
  for (int u = 0; u < 4; ++u) red[(4 * ti + u) * 16 + tj] = lacc[u];
  __syncthreads();
  if (tid < 64) {
    float t = 0.0f;
    for (int q = 0; q < 16; ++q) t += red[tid * 16 + q];
    pl[(size_t)sl * 4096 + abase + tid] = t;
  }
  __syncthreads();
  #pragma unroll
  for (int u = 0; u < 4; ++u) red[(4 * ti + u) * 16 + tj] = Sacc[u];
  __syncthreads();
  if (tid < 64) {
    float t = 0.0f;
    for (int q = 0; q < 16; ++q) t += red[tid * 16 + q];
    pS[(size_t)sl * 4096 + abase + tid] = t;
  }
  __syncthreads();
  #pragma unroll
  for (int u = 0; u < 4; ++u) red[(4 * ti + u) * 16 + tj] = Pacc[u];
  __syncthreads();
  if (tid < 64) {
    float t = 0.0f;
    for (int q = 0; q < 16; ++q) t += red[tid * 16 + q];
    pP[(size_t)sl * 4096 + abase + tid] = t;
  }
}

// ---------------- kernel 4: finalize (deterministic, single block) ----------------
__global__ __launch_bounds__(256) void k_final(
    const float* __restrict__ part, float* __restrict__ out)
{
  const float* pl = part;
  const float* pS = part + 8 * 4096;
  const float* pP = part + 16 * 4096;
  __shared__ float red[256];
  float tot = 0.0f;
  for (int a = threadIdx.x; a < N_ROWS; a += 256) {
    float l = 0.0f, S = 0.0f, P = 0.0f;
    #pragma unroll
    for (int sg = 0; sg < 8; ++sg) {
      l += pl[sg * 4096 + a];
      S += pS[sg * 4096 + a];
      P += pP[sg * 4096 + a];
    }
    const float np = fmaxf(P, 1.0f);
    // loss_a = m + log(denom + 1e-8) - mean_pos(sim);  m = 1/tau (shift-invariant)
    tot += INV_TAU + logf(l + 1e-8f) - (S * INV_TAU) / np;
  }
  red[threadIdx.x] = tot;
  __syncthreads();
  for (int off = 128; off > 0; off >>= 1) {
    if (threadIdx.x < off) red[threadIdx.x] += red[threadIdx.x + off];
    __syncthreads();
  }
  if (threadIdx.x == 0) out[0] = red[0] / (float)N_ROWS;
}

extern "C" void kernel_launch(void* const* d_in, const int* in_sizes, int n_in,
                              void* d_out, int out_size, void* d_ws, size_t ws_size,
                              hipStream_t stream) {
  const float* z1 = (const float*)d_in[0];
  const float* z2 = (const float*)d_in[1];
  const int* labels = (const int*)d_in[2];
  float* out = (float*)d_out;
  char* ws = (char*)d_ws;

  float* zall            = (float*)(ws);
  unsigned long long* bm = (unsigned long long*)(ws + 4194304);
  float* s               = (float*)(ws + 4456448);
  unsigned int* pm       = (unsigned int*)(ws + 4472832);
  float* part            = (float*)(ws + 6569984);

  hipLaunchKernelGGL(k_norm_pack, dim3(2 * N_ROWS), dim3(64), 0, stream,
                     z1, z2, labels, zall, bm, s);
  hipLaunchKernelGGL(k_posmask, dim3(2048), dim3(256), 0, stream,
                     (const unsigned int*)bm, s, pm);
  hipLaunchKernelGGL(k_main, dim3(64, 8), dim3(256), 0, stream,
                     zall, pm, part);
  hipLaunchKernelGGL(k_final, dim3(1), dim3(256), 0, stream, part, out);
}

// Round 2
// 259.332 us; speedup vs baseline: 26.4617x; 26.4617x over previous
//
#include <hip/hip_runtime.h>
#include <math.h>

#define N_ROWS 4096
#define DIM    128
#define A_LAB  512
#define INV_TAU 14.285714285714286f
#define THR 0.3f

typedef __attribute__((ext_vector_type(8))) short short8;   // 8 bf16 (4 VGPRs)
typedef __attribute__((ext_vector_type(4))) float f32x4;    // MFMA C/D frag

// ---------------- workspace layout (bytes) ----------------
// zbf   u16 [8192*128]  @ 0          (2,097,152)
// bm    u64 [4096*8]    @ 2,097,152  (262,144)
// s     f32 [4096]      @ 2,359,296  (16,384)
// pm    u32 [4096*128]  @ 2,375,680  (2,097,152)
// part  f32 [64*3*4096] @ 4,472,832  (3,145,728)
// loss  f32 [4096]      @ 7,618,560  (16,384)      total ~7.63 MB

__device__ __forceinline__ unsigned short f2bf(float f) {
  unsigned int u = __builtin_bit_cast(unsigned int, f);
  u += 0x7fffu + ((u >> 16) & 1u);            // round-to-nearest-even
  return (unsigned short)(u >> 16);
}

// ---------------- kernel 1: L2-normalize (-> bf16) + bit-pack labels ----------------
__global__ __launch_bounds__(64) void k_norm_pack(
    const float* __restrict__ z1, const float* __restrict__ z2,
    const int* __restrict__ labels,
    unsigned int* __restrict__ zbf, unsigned long long* __restrict__ bm,
    float* __restrict__ s)
{
  const int r = blockIdx.x;           // 0..8191
  const int t = threadIdx.x;          // 0..63 (one wave)
  const float* src = (r < N_ROWS) ? (z1 + (size_t)r * DIM)
                                  : (z2 + (size_t)(r - N_ROWS) * DIM);
  float2 x = *(const float2*)(src + 2 * t);
  float ss = x.x * x.x + x.y * x.y;
  #pragma unroll
  for (int off = 32; off > 0; off >>= 1) ss += __shfl_xor(ss, off);
  const float inv = 1.0f / fmaxf(sqrtf(ss), 1e-12f);
  const unsigned int lo = f2bf(x.x * inv);
  const unsigned int hi = f2bf(x.y * inv);
  zbf[(size_t)r * 64 + t] = (hi << 16) | lo;

  if (r < N_ROWS) {
    const int* lab = labels + (size_t)r * A_LAB;
    unsigned long long myword = 0ull;
    #pragma unroll
    for (int c = 0; c < 8; ++c) {
      unsigned long long mm = __ballot(lab[c * 64 + t] != 0);
      if (t == c) myword = mm;
    }
    int p = (t < 8) ? __popcll(myword) : 0;
    #pragma unroll
    for (int off = 32; off > 0; off >>= 1) p += __shfl_xor(p, off);
    if (t < 8) bm[(size_t)r * 8 + t] = myword;
    if (t == 0) s[r] = (float)p;
  }
}

// ---------------- kernel 2: Jaccard positive mask (bit per pair) ----------------
__global__ __launch_bounds__(256) void k_posmask(
    const unsigned int* __restrict__ bm, const float* __restrict__ s,
    unsigned int* __restrict__ pm)
{
  const int g = blockIdx.x * 256 + threadIdx.x;  // 0..524287 == i*128+w
  const int i = g >> 7;
  const int w = g & 127;
  const uint4* bi = (const uint4*)(bm + (size_t)i * 16);
  const uint4 a0 = bi[0], a1 = bi[1], a2 = bi[2], a3 = bi[3];
  const float si = s[i];
  unsigned int bits = 0u;
  int jc = w << 5;
  for (int jj = 0; jj < 32; ++jj, ++jc) {
    const uint4* bj = (const uint4*)(bm + (size_t)jc * 16);
    const uint4 b0 = bj[0], b1 = bj[1], b2 = bj[2], b3 = bj[3];
    int inter = __popc(a0.x & b0.x) + __popc(a0.y & b0.y)
              + __popc(a0.z & b0.z) + __popc(a0.w & b0.w)
              + __popc(a1.x & b1.x) + __popc(a1.y & b1.y)
              + __popc(a1.z & b1.z) + __popc(a1.w & b1.w)
              + __popc(a2.x & b2.x) + __popc(a2.y & b2.y)
              + __popc(a2.z & b2.z) + __popc(a2.w & b2.w)
              + __popc(a3.x & b3.x) + __popc(a3.y & b3.y)
              + __popc(a3.z & b3.z) + __popc(a3.w & b3.w);
    const float fin = (float)inter;
    const float un = si + s[jc] - fin;
    const float jac = fin / (un + 1e-8f);
    if (jac >= THR) bits |= (1u << jj);
  }
  pm[g] = bits;
}

// ---------------- kernel 3: MFMA sim-GEMM + fused masked-softmax partials ------
// Tile: 128 anchors x 128 cols, K=128 in one shot. 4 waves, each 32 rows x 128 cols.
// LDS tiles stored as 16B units, XOR-swizzled: unit(row,u) -> row*16 + (u ^ (row&15)).
// MFMA 16x16x32 bf16: A/B frag = 8 contiguous bf16 at [m=lane&15][k=quad*8..+8);
// C/D frag: col=lane&15, row=quad*4+reg (verified m89/m91).
__global__ __launch_bounds__(256, 2) void k_main(
    const unsigned short* __restrict__ zbf, const unsigned int* __restrict__ pm,
    float* __restrict__ part)
{
  __shared__ unsigned short lds[2 * 128 * 128];  // A @0 (32KB), B @128*128 (32KB)
  const int tid = threadIdx.x;
  const int abase = blockIdx.x * 128;   // 32 anchor tiles
  const int cbase = blockIdx.y * 128;   // 64 column tiles over 2N

  {
    const uint4* gA = (const uint4*)(zbf + (size_t)abase * 128);
    const uint4* gB = (const uint4*)(zbf + (size_t)cbase * 128);
    uint4* sA = (uint4*)lds;
    uint4* sB = (uint4*)(lds + 128 * 128);
    #pragma unroll
    for (int p = 0; p < 8; ++p) {
      const int g = p * 256 + tid;       // 0..2047 units
      const int r = g >> 4, u = g & 15;
      const int d = r * 16 + (u ^ (r & 15));
      sA[d] = gA[g];
      sB[d] = gB[g];
    }
  }
  __syncthreads();

  const int wave = tid >> 6, lane = tid & 63;
  const int col = lane & 15, quad = lane >> 4;
  const int wrow = wave * 32;                    // this wave: rows [wrow, wrow+32)
  const uint4* sAu = (const uint4*)lds;
  const uint4* sBu = (const uint4*)(lds + 128 * 128);

  short8 afr[2][4];
  #pragma unroll
  for (int rt = 0; rt < 2; ++rt)
    #pragma unroll
    for (int kf = 0; kf < 4; ++kf) {
      const int r = wrow + rt * 16 + col;
      const int u = kf * 4 + quad;
      afr[rt][kf] = *(const short8*)&sAu[r * 16 + (u ^ (r & 15))];
    }

  f32x4 acc[2][8];
  #pragma unroll
  for (int rt = 0; rt < 2; ++rt)
    #pragma unroll
    for (int nt = 0; nt < 8; ++nt) acc[rt][nt] = (f32x4){0, 0, 0, 0};

  #pragma unroll
  for (int nt = 0; nt < 8; ++nt) {
    short8 bfr[4];
    #pragma unroll
    for (int kf = 0; kf < 4; ++kf) {
      const int r = nt * 16 + col;
      const int u = kf * 4 + quad;
      bfr[kf] = *(const short8*)&sBu[r * 16 + (u ^ (r & 15))];
    }
    #pragma unroll
    for (int rt = 0; rt < 2; ++rt)
      #pragma unroll
      for (int kf = 0; kf < 4; ++kf)
        acc[rt][nt] = __builtin_amdgcn_mfma_f32_16x16x32_bf16(
            afr[rt][kf], bfr[kf], acc[rt][nt], 0, 0, 0);
  }

  // ---- epilogue: fixed shift m = 1/tau (loss shift-invariant); skip self col ----
  const bool left = (cbase < N_ROWS);            // block-uniform
  const int cw0 = (cbase & (N_ROWS - 1)) >> 5;   // first of 4 pm words for this tile
  float lacc[2][4], Sacc[2][4], Pcnt[2][4];
  #pragma unroll
  for (int rt = 0; rt < 2; ++rt)
    #pragma unroll
    for (int reg = 0; reg < 4; ++reg) { lacc[rt][reg] = 0; Sacc[rt][reg] = 0; Pcnt[rt][reg] = 0; }

  #pragma unroll
  for (int rt = 0; rt < 2; ++rt) {
    unsigned int pw[4][4];
    #pragma unroll
    for (int reg = 0; reg < 4; ++reg) {
      const int i = abase + wrow + rt * 16 + quad * 4 + reg;
      #pragma unroll
      for (int w = 0; w < 4; ++w) pw[reg][w] = pm[(size_t)i * 128 + cw0 + w];
    }
    #pragma unroll
    for (int nt = 0; nt < 8; ++nt) {
      const int j = cbase + nt * 16 + col;
      const int jc = j & (N_ROWS - 1);
      const int bitpos = jc & 31;
      const int w = nt >> 1;
      #pragma unroll
      for (int reg = 0; reg < 4; ++reg) {
        const int i = abase + wrow + rt * 16 + quad * 4 + reg;
        const float d = acc[rt][nt][reg];
        const bool bit = (pw[reg][w] >> bitpos) & 1;
        const bool self = left && (j == i);
        const bool pos = left ? (bit && !self) : (bit || (jc == i));
        const float e = __expf((d - 1.0f) * INV_TAU);
        if (!self) lacc[rt][reg] += e;
        if (pos) { Sacc[rt][reg] += d; Pcnt[rt][reg] += 1.0f; }
      }
    }
  }

  // ---- reduce across the 16 col-lanes (bits 0..3 of lane), write per-slice ----
  #pragma unroll
  for (int rt = 0; rt < 2; ++rt)
    #pragma unroll
    for (int reg = 0; reg < 4; ++reg) {
      float l = lacc[rt][reg], S = Sacc[rt][reg], P = Pcnt[rt][reg];
      #pragma unroll
      for (int m = 1; m < 16; m <<= 1) {
        l += __shfl_xor(l, m);
        S += __shfl_xor(S, m);
        P += __shfl_xor(P, m);
      }
      if (col == 0) {
        const int i = abase + wrow + rt * 16 + quad * 4 + reg;
        float* base = part + (size_t)blockIdx.y * 3 * 4096;
        base[i] = l;
        base[4096 + i] = S;
        base[8192 + i] = P;
      }
    }
}

// ---------------- kernel 4a: per-anchor loss (16 blocks) ----------------
__global__ __launch_bounds__(256) void k_loss(
    const float* __restrict__ part, float* __restrict__ loss)
{
  const int a = blockIdx.x * 256 + threadIdx.x;   // 0..4095
  float l = 0.0f, S = 0.0f, P = 0.0f;
  for (int by = 0; by < 64; ++by) {
    const float* b = part + (size_t)by * 3 * 4096;
    l += b[a];
    S += b[4096 + a];
    P += b[8192 + a];
  }
  const float np = fmaxf(P, 1.0f);
  loss[a] = INV_TAU + logf(l + 1e-8f) - (S * INV_TAU) / np;
}

// ---------------- kernel 4b: final reduce (1 block) ----------------
__global__ __launch_bounds__(256) void k_final(
    const float* __restrict__ loss, float* __restrict__ out)
{
  __shared__ float red[256];
  float t = 0.0f;
  for (int a = threadIdx.x; a < N_ROWS; a += 256) t += loss[a];
  red[threadIdx.x] = t;
  __syncthreads();
  for (int off = 128; off > 0; off >>= 1) {
    if (threadIdx.x < off) red[threadIdx.x] += red[threadIdx.x + off];
    __syncthreads();
  }
  if (threadIdx.x == 0) out[0] = red[0] / (float)N_ROWS;
}

extern "C" void kernel_launch(void* const* d_in, const int* in_sizes, int n_in,
                              void* d_out, int out_size, void* d_ws, size_t ws_size,
                              hipStream_t stream) {
  const float* z1 = (const float*)d_in[0];
  const float* z2 = (const float*)d_in[1];
  const int* labels = (const int*)d_in[2];
  float* out = (float*)d_out;
  char* ws = (char*)d_ws;

  unsigned int* zbf      = (unsigned int*)(ws);
  unsigned long long* bm = (unsigned long long*)(ws + 2097152);
  float* s               = (float*)(ws + 2359296);
  unsigned int* pm       = (unsigned int*)(ws + 2375680);
  float* part            = (float*)(ws + 4472832);
  float* loss            = (float*)(ws + 7618560);

  hipLaunchKernelGGL(k_norm_pack, dim3(2 * N_ROWS), dim3(64), 0, stream,
                     z1, z2, labels, zbf, bm, s);
  hipLaunchKernelGGL(k_posmask, dim3(2048), dim3(256), 0, stream,
                     (const unsigned int*)bm, s, pm);
  hipLaunchKernelGGL(k_main, dim3(32, 64), dim3(256), 0, stream,
                     (const unsigned short*)zbf, pm, part);
  hipLaunchKernelGGL(k_loss, dim3(16), dim3(256), 0, stream, part, loss);
  hipLaunchKernelGGL(k_final, dim3(1), dim3(256), 0, stream, loss, out);
}

// Round 3
// 129.361 us; speedup vs baseline: 53.0481x; 2.0047x over previous
//
#include <hip/hip_runtime.h>
#include <math.h>

#define N_ROWS 4096
#define DIM    128
#define A_LAB  512
#define INV_TAU 14.285714285714286f

typedef __attribute__((ext_vector_type(8))) short short8;   // 8 bf16 (4 VGPRs)
typedef __attribute__((ext_vector_type(4))) float f32x4;    // MFMA C/D frag (16x16)
typedef __attribute__((ext_vector_type(4))) int i32x4;      // i8 MFMA A/B frag
typedef __attribute__((ext_vector_type(16))) int i32x16;    // i8 MFMA C/D frag (32x32)

// ---------------- workspace layout (bytes) ----------------
// zbf   u16 [8192*128]   @ 0          (2,097,152)
// labs8 i8  [4096*512]   @ 2,097,152  (2,097,152)
// s     i32 [4096]       @ 4,194,304  (16,384)
// pm    u32 [4096*128]   @ 4,210,688  (2,097,152)
// part  f32 [64*3*4096]  @ 6,307,840  (3,145,728)
// loss  f32 [4096]       @ 9,453,568  (16,384)     total ~9.47 MB

__device__ __forceinline__ unsigned short f2bf(float f) {
  unsigned int u = __builtin_bit_cast(unsigned int, f);
  u += 0x7fffu + ((u >> 16) & 1u);            // round-to-nearest-even
  return (unsigned short)(u >> 16);
}

// ------------ kernel 1: L2-normalize (-> bf16) + labels -> i8 + row-popcount ------------
__global__ __launch_bounds__(256) void k_norm_pack(
    const float* __restrict__ z1, const float* __restrict__ z2,
    const int* __restrict__ labels,
    unsigned int* __restrict__ zbf, unsigned char* __restrict__ labs8,
    int* __restrict__ s)
{
  const int wave = threadIdx.x >> 6, lane = threadIdx.x & 63;
  const int r = blockIdx.x * 4 + wave;         // 0..8191
  const float* src = (r < N_ROWS) ? (z1 + (size_t)r * DIM)
                                  : (z2 + (size_t)(r - N_ROWS) * DIM);
  float2 x = ((const float2*)src)[lane];
  float ss = x.x * x.x + x.y * x.y;
  #pragma unroll
  for (int off = 32; off > 0; off >>= 1) ss += __shfl_xor(ss, off);
  const float inv = 1.0f / fmaxf(sqrtf(ss), 1e-12f);
  const unsigned int lo = f2bf(x.x * inv);
  const unsigned int hi = f2bf(x.y * inv);
  zbf[(size_t)r * 64 + lane] = (hi << 16) | lo;

  if (r < N_ROWS) {
    const int4* lp = (const int4*)(labels + (size_t)r * A_LAB);
    const int4 a = lp[2 * lane], b = lp[2 * lane + 1];
    const unsigned int w0 = (unsigned int)(a.x != 0)       | ((unsigned int)(a.y != 0) << 8)
                          | ((unsigned int)(a.z != 0) << 16) | ((unsigned int)(a.w != 0) << 24);
    const unsigned int w1 = (unsigned int)(b.x != 0)       | ((unsigned int)(b.y != 0) << 8)
                          | ((unsigned int)(b.z != 0) << 16) | ((unsigned int)(b.w != 0) << 24);
    uint2 v; v.x = w0; v.y = w1;
    ((uint2*)labs8)[(size_t)r * 64 + lane] = v;   // 8 bytes per thread, row = 512 B
    int cnt = __popc(w0) + __popc(w1);            // bytes are 0/1 -> popc == byte sum
    #pragma unroll
    for (int off = 32; off > 0; off >>= 1) cnt += __shfl_xor(cnt, off);
    if (lane == 0) s[r] = cnt;
  }
}

// ------------ kernel 2: Jaccard positive mask via i8 MFMA GEMM ------------
// inter[i][j] = labs8[i] . labs8[j]  (K=512, i8->i32, exact)
// pos bit: jac >= 0.3  <=>  13*inter >= 3*(s_i + s_j)   (exact integer form)
// Tile 128x128 per block; 4 waves in 2x2; each wave 64x64 = 2x2 subtiles of 32x32.
// LDS: rows as 8 x 16B units, unit (r,u) -> r*8 + (u ^ (r&7)).
// mfma_i32_32x32x32_i8: A/B frag = 16 contiguous k-bytes at [m=lane&31][k=32*ks+16*(lane>>5)];
// C/D: col=lane&31, row=(reg&3)+8*(reg>>2)+4*(lane>>5)  (m74/m101, dtype-independent).
__global__ __launch_bounds__(256, 2) void k_jac(
    const unsigned char* __restrict__ labs8, const int* __restrict__ s,
    unsigned int* __restrict__ pm)
{
  __shared__ uint4 lds[2048];                 // A units [0,1024), B units [1024,2048)
  const int tid = threadIdx.x;
  const int ibase = blockIdx.x * 128, jbase = blockIdx.y * 128;
  const int wave = tid >> 6, lane = tid & 63;
  const int wrow = (wave >> 1) * 64, wcol = (wave & 1) * 64;
  const int col = lane & 31, h = lane >> 5;

  i32x16 acc[2][2];
  #pragma unroll
  for (int rt = 0; rt < 2; ++rt)
    #pragma unroll
    for (int nt = 0; nt < 2; ++nt)
      #pragma unroll
      for (int e = 0; e < 16; ++e) acc[rt][nt][e] = 0;

  for (int ck = 0; ck < 4; ++ck) {            // K chunks of 128 bytes
    __syncthreads();
    #pragma unroll
    for (int p = 0; p < 4; ++p) {
      const int g = p * 256 + tid;            // 0..1023 units
      const int r = g >> 3, u = g & 7;
      const int d = r * 8 + (u ^ (r & 7));
      lds[d]        = *(const uint4*)(labs8 + (((size_t)(ibase + r)) << 9) + ck * 128 + u * 16);
      lds[1024 + d] = *(const uint4*)(labs8 + (((size_t)(jbase + r)) << 9) + ck * 128 + u * 16);
    }
    __syncthreads();

    #pragma unroll
    for (int ks = 0; ks < 4; ++ks) {          // 32 k-bytes per step
      const int u = ks * 2 + h;
      i32x4 a[2], b[2];
      #pragma unroll
      for (int rt = 0; rt < 2; ++rt) {
        const int m = wrow + rt * 32 + col;
        a[rt] = *(const i32x4*)&lds[m * 8 + (u ^ (m & 7))];
      }
      #pragma unroll
      for (int nt = 0; nt < 2; ++nt) {
        const int m = wcol + nt * 32 + col;
        b[nt] = *(const i32x4*)&lds[1024 + m * 8 + (u ^ (m & 7))];
      }
      #pragma unroll
      for (int rt = 0; rt < 2; ++rt)
        #pragma unroll
        for (int nt = 0; nt < 2; ++nt)
          acc[rt][nt] = __builtin_amdgcn_mfma_i32_32x32x32_i8(a[rt], b[nt], acc[rt][nt], 0, 0, 0);
    }
  }

  // ---- epilogue: threshold + ballot -> pm u32 words ----
  int sj[2];
  #pragma unroll
  for (int nt = 0; nt < 2; ++nt) sj[nt] = s[jbase + wcol + nt * 32 + col];

  #pragma unroll
  for (int rt = 0; rt < 2; ++rt) {
    int si[16];
    #pragma unroll
    for (int reg = 0; reg < 16; ++reg) {
      const int row = (reg & 3) + 8 * (reg >> 2) + 4 * h;
      si[reg] = s[ibase + wrow + rt * 32 + row];
    }
    #pragma unroll
    for (int nt = 0; nt < 2; ++nt) {
      const int w = (jbase + wcol + nt * 32) >> 5;
      #pragma unroll
      for (int reg = 0; reg < 16; ++reg) {
        const int inter = acc[rt][nt][reg];
        const bool pred = 13 * inter >= 3 * (si[reg] + sj[nt]);
        const unsigned long long bal = __ballot(pred);
        const int r0 = (reg & 3) + 8 * (reg >> 2);
        const int i0 = ibase + wrow + rt * 32 + r0;
        if (lane == 0)      pm[(size_t)i0 * 128 + w]       = (unsigned int)bal;
        else if (lane == 1) pm[(size_t)(i0 + 4) * 128 + w] = (unsigned int)(bal >> 32);
      }
    }
  }
}

// ---------------- kernel 3: MFMA sim-GEMM + fused masked-softmax partials ------
__global__ __launch_bounds__(256, 2) void k_main(
    const unsigned short* __restrict__ zbf, const unsigned int* __restrict__ pm,
    float* __restrict__ part)
{
  __shared__ unsigned short lds[2 * 128 * 128];  // A @0 (32KB), B @128*128 (32KB)
  const int tid = threadIdx.x;
  const int abase = blockIdx.x * 128;   // 32 anchor tiles
  const int cbase = blockIdx.y * 128;   // 64 column tiles over 2N

  {
    const uint4* gA = (const uint4*)(zbf + (size_t)abase * 128);
    const uint4* gB = (const uint4*)(zbf + (size_t)cbase * 128);
    uint4* sA = (uint4*)lds;
    uint4* sB = (uint4*)(lds + 128 * 128);
    #pragma unroll
    for (int p = 0; p < 8; ++p) {
      const int g = p * 256 + tid;       // 0..2047 units
      const int r = g >> 4, u = g & 15;
      const int d = r * 16 + (u ^ (r & 15));
      sA[d] = gA[g];
      sB[d] = gB[g];
    }
  }
  __syncthreads();

  const int wave = tid >> 6, lane = tid & 63;
  const int col = lane & 15, quad = lane >> 4;
  const int wrow = wave * 32;                    // this wave: rows [wrow, wrow+32)
  const uint4* sAu = (const uint4*)lds;
  const uint4* sBu = (const uint4*)(lds + 128 * 128);

  short8 afr[2][4];
  #pragma unroll
  for (int rt = 0; rt < 2; ++rt)
    #pragma unroll
    for (int kf = 0; kf < 4; ++kf) {
      const int r = wrow + rt * 16 + col;
      const int u = kf * 4 + quad;
      afr[rt][kf] = *(const short8*)&sAu[r * 16 + (u ^ (r & 15))];
    }

  f32x4 acc[2][8];
  #pragma unroll
  for (int rt = 0; rt < 2; ++rt)
    #pragma unroll
    for (int nt = 0; nt < 8; ++nt) acc[rt][nt] = (f32x4){0, 0, 0, 0};

  #pragma unroll
  for (int nt = 0; nt < 8; ++nt) {
    short8 bfr[4];
    #pragma unroll
    for (int kf = 0; kf < 4; ++kf) {
      const int r = nt * 16 + col;
      const int u = kf * 4 + quad;
      bfr[kf] = *(const short8*)&sBu[r * 16 + (u ^ (r & 15))];
    }
    #pragma unroll
    for (int rt = 0; rt < 2; ++rt)
      #pragma unroll
      for (int kf = 0; kf < 4; ++kf)
        acc[rt][nt] = __builtin_amdgcn_mfma_f32_16x16x32_bf16(
            afr[rt][kf], bfr[kf], acc[rt][nt], 0, 0, 0);
  }

  // ---- epilogue: fixed shift m = 1/tau (loss shift-invariant); skip self col ----
  const bool left = (cbase < N_ROWS);            // block-uniform
  const int cw0 = (cbase & (N_ROWS - 1)) >> 5;   // first of 4 pm words for this tile
  float lacc[2][4], Sacc[2][4], Pcnt[2][4];
  #pragma unroll
  for (int rt = 0; rt < 2; ++rt)
    #pragma unroll
    for (int reg = 0; reg < 4; ++reg) { lacc[rt][reg] = 0; Sacc[rt][reg] = 0; Pcnt[rt][reg] = 0; }

  #pragma unroll
  for (int rt = 0; rt < 2; ++rt) {
    unsigned int pw[4][4];
    #pragma unroll
    for (int reg = 0; reg < 4; ++reg) {
      const int i = abase + wrow + rt * 16 + quad * 4 + reg;
      #pragma unroll
      for (int w = 0; w < 4; ++w) pw[reg][w] = pm[(size_t)i * 128 + cw0 + w];
    }
    #pragma unroll
    for (int nt = 0; nt < 8; ++nt) {
      const int j = cbase + nt * 16 + col;
      const int jc = j & (N_ROWS - 1);
      const int bitpos = jc & 31;
      const int w = nt >> 1;
      #pragma unroll
      for (int reg = 0; reg < 4; ++reg) {
        const int i = abase + wrow + rt * 16 + quad * 4 + reg;
        const float d = acc[rt][nt][reg];
        const bool bit = (pw[reg][w] >> bitpos) & 1;
        const bool self = left && (j == i);
        const bool pos = left ? (bit && !self) : (bit || (jc == i));
        const float e = __expf((d - 1.0f) * INV_TAU);
        if (!self) lacc[rt][reg] += e;
        if (pos) { Sacc[rt][reg] += d; Pcnt[rt][reg] += 1.0f; }
      }
    }
  }

  // ---- reduce across the 16 col-lanes, write per-slice partials ----
  #pragma unroll
  for (int rt = 0; rt < 2; ++rt)
    #pragma unroll
    for (int reg = 0; reg < 4; ++reg) {
      float l = lacc[rt][reg], S = Sacc[rt][reg], P = Pcnt[rt][reg];
      #pragma unroll
      for (int m = 1; m < 16; m <<= 1) {
        l += __shfl_xor(l, m);
        S += __shfl_xor(S, m);
        P += __shfl_xor(P, m);
      }
      if (col == 0) {
        const int i = abase + wrow + rt * 16 + quad * 4 + reg;
        float* base = part + (size_t)blockIdx.y * 3 * 4096;
        base[i] = l;
        base[4096 + i] = S;
        base[8192 + i] = P;
      }
    }
}

// ---------------- kernel 4a: per-anchor loss ----------------
__global__ __launch_bounds__(128) void k_loss(
    const float* __restrict__ part, float* __restrict__ loss)
{
  const int a = blockIdx.x * 128 + threadIdx.x;   // 0..4095
  float l = 0.0f, S = 0.0f, P = 0.0f;
  #pragma unroll 8
  for (int by = 0; by < 64; ++by) {
    const float* b = part + (size_t)by * 3 * 4096;
    l += b[a];
    S += b[4096 + a];
    P += b[8192 + a];
  }
  const float np = fmaxf(P, 1.0f);
  loss[a] = INV_TAU + logf(l + 1e-8f) - (S * INV_TAU) / np;
}

// ---------------- kernel 4b: final reduce (1 block) ----------------
__global__ __launch_bounds__(256) void k_final(
    const float* __restrict__ loss, float* __restrict__ out)
{
  __shared__ float red[256];
  float t = 0.0f;
  for (int a = threadIdx.x; a < N_ROWS; a += 256) t += loss[a];
  red[threadIdx.x] = t;
  __syncthreads();
  for (int off = 128; off > 0; off >>= 1) {
    if (threadIdx.x < off) red[threadIdx.x] += red[threadIdx.x + off];
    __syncthreads();
  }
  if (threadIdx.x == 0) out[0] = red[0] / (float)N_ROWS;
}

extern "C" void kernel_launch(void* const* d_in, const int* in_sizes, int n_in,
                              void* d_out, int out_size, void* d_ws, size_t ws_size,
                              hipStream_t stream) {
  const float* z1 = (const float*)d_in[0];
  const float* z2 = (const float*)d_in[1];
  const int* labels = (const int*)d_in[2];
  float* out = (float*)d_out;
  char* ws = (char*)d_ws;

  unsigned int* zbf    = (unsigned int*)(ws);
  unsigned char* labs8 = (unsigned char*)(ws + 2097152);
  int* s               = (int*)(ws + 4194304);
  unsigned int* pm     = (unsigned int*)(ws + 4210688);
  float* part          = (float*)(ws + 6307840);
  float* loss          = (float*)(ws + 9453568);

  hipLaunchKernelGGL(k_norm_pack, dim3(2048), dim3(256), 0, stream,
                     z1, z2, labels, zbf, labs8, s);
  hipLaunchKernelGGL(k_jac, dim3(32, 32), dim3(256), 0, stream,
                     labs8, s, pm);
  hipLaunchKernelGGL(k_main, dim3(32, 64), dim3(256), 0, stream,
                     (const unsigned short*)zbf, pm, part);
  hipLaunchKernelGGL(k_loss, dim3(32), dim3(128), 0, stream, part, loss);
  hipLaunchKernelGGL(k_final, dim3(1), dim3(256), 0, stream, loss, out);
}